// Round 3
// baseline (316.979 us; speedup 1.0000x reference)
//
#include <hip/hip_runtime.h>

// Fused single-kernel blocked parallel linear scan for
//   x_{k+1} = A x_k + B u_k,  y_k = C x_k + D u_k   (N=16384, R=256, NX=8)
// 512 persistent blocks (2/CU, co-resident by construction) with device-scope
// grid barriers. Phases:
//   P0: every block computes A^32/64/96/128 in its own LDS (tiny)
//   PA: block c computes zero-state response d32[c] of its 32-step chunk
//   PB: blocks 0..127 combine 4 d32 -> d128[m]
//   PC: block 0 serial-scans 128 super-chunks -> s128 (depth-4 prefetch)
//   PD: block c replays its chunk from known start; nt-stores X and y

#define NSTEPS 16384
#define NUI 2
#define RB 256
#define NXS 8
#define NYO 2
#define LF 32
#define NC1 (NSTEPS / LF)  // 512 fine chunks == grid size
#define NC2 (NC1 / 4)      // 128 super-chunks
#define NBLK NC1
#define GRPSH 5            // 32 blocks per barrier group
#define NGRP (NBLK >> GRPSH)  // 16 groups

// Hierarchical grid barrier. Counters accumulate across phases (no reset).
// bar layout: group g counter at bar[g*32], root at bar[NGRP*32].
__device__ __forceinline__ void grid_sync(unsigned* bar, int bid, unsigned phase) {
    __syncthreads();                      // drains each wave's vmem (stores in L2)
    if (threadIdx.x == 0) {
        __threadfence();                  // release: L2 writeback, agent scope
        unsigned* grp  = bar + ((bid >> GRPSH) << 5);
        unsigned* root = bar + (NGRP << 5);
        unsigned o = __hip_atomic_fetch_add(grp, 1u, __ATOMIC_RELAXED,
                                            __HIP_MEMORY_SCOPE_AGENT);
        if ((o & 31u) == 31u)
            __hip_atomic_fetch_add(root, 1u, __ATOMIC_RELAXED,
                                   __HIP_MEMORY_SCOPE_AGENT);
        const unsigned tgt = phase * (unsigned)NGRP;
        while (__hip_atomic_load(root, __ATOMIC_RELAXED,
                                 __HIP_MEMORY_SCOPE_AGENT) < tgt)
            __builtin_amdgcn_s_sleep(1);
        __threadfence();                  // acquire: L1/L2 invalidate
    }
    __syncthreads();
}

__global__ __launch_bounds__(256, 2) void fused_scan_k(
    const float* __restrict__ u, const float* __restrict__ x0,
    const float* __restrict__ A, const float* __restrict__ Bu,
    const float* __restrict__ Cy, const float* __restrict__ Dyu,
    const float* __restrict__ um, const float* __restrict__ us,
    const float* __restrict__ ym, const float* __restrict__ ys,
    float* __restrict__ Y, float* __restrict__ X,
    float* __restrict__ d32, float* __restrict__ d128,
    float* __restrict__ s128, unsigned* __restrict__ bar) {
    __shared__ float P32[64], P64[64], P96[64], P128[64], Mt[64];
    const int tid = threadIdx.x;
    const int c = blockIdx.x;  // fine chunk id, 0..511
    const int li = tid >> 3, lj = tid & 7;

    // ---------------- P0: A powers in LDS ----------------
    if (tid < 64) Mt[tid] = A[tid];
    __syncthreads();
    for (int it = 0; it < 5; ++it) {  // -> A^32
        float acc = 0.f;
        if (tid < 64) {
            #pragma unroll
            for (int k = 0; k < 8; ++k) acc += Mt[li * 8 + k] * Mt[k * 8 + lj];
        }
        __syncthreads();
        if (tid < 64) Mt[tid] = acc;
        __syncthreads();
    }
    if (tid < 64) P32[tid] = Mt[tid];
    {   // -> A^64
        float acc = 0.f;
        if (tid < 64) {
            #pragma unroll
            for (int k = 0; k < 8; ++k) acc += Mt[li * 8 + k] * Mt[k * 8 + lj];
        }
        __syncthreads();
        if (tid < 64) Mt[tid] = acc;
        __syncthreads();
    }
    if (tid < 64) {
        float a96 = 0.f, a128 = 0.f;
        #pragma unroll
        for (int k = 0; k < 8; ++k) {
            a96  += Mt[li * 8 + k] * P32[k * 8 + lj];
            a128 += Mt[li * 8 + k] * Mt[k * 8 + lj];
        }
        P64[tid] = Mt[tid];
        P96[tid] = a96;
        P128[tid] = a128;
    }
    __syncthreads();

    const float um0 = um[0], um1 = um[1];
    const float is0 = 1.0f / us[0], is1 = 1.0f / us[1];

    // ---------------- PA: zero-state response d32[c] ----------------
    {
        float a[NXS][NXS];
        #pragma unroll
        for (int i = 0; i < NXS; ++i)
            #pragma unroll
            for (int j = 0; j < NXS; ++j) a[i][j] = A[i * NXS + j];
        float b0[NXS], b1[NXS];
        #pragma unroll
        for (int i = 0; i < NXS; ++i) {
            b0[i] = Bu[i * NUI];
            b1[i] = Bu[i * NUI + 1];
        }
        float t[NXS];
        #pragma unroll
        for (int i = 0; i < NXS; ++i) t[i] = 0.f;
        const float* up = u + (size_t)c * LF * NUI * RB + tid;
        #pragma unroll 4
        for (int j = 0; j < LF; ++j) {
            const float u0 = (up[0]  - um0) * is0;
            const float u1 = (up[RB] - um1) * is1;
            up += NUI * RB;
            float nt[NXS];
            #pragma unroll
            for (int i = 0; i < NXS; ++i) {
                float acc = fmaf(b0[i], u0, b1[i] * u1);
                #pragma unroll
                for (int k = 0; k < NXS; ++k) acc = fmaf(a[i][k], t[k], acc);
                nt[i] = acc;
            }
            #pragma unroll
            for (int i = 0; i < NXS; ++i) t[i] = nt[i];
        }
        float* dp = d32 + (size_t)c * NXS * RB + tid;
        #pragma unroll
        for (int i = 0; i < NXS; ++i) dp[i * RB] = t[i];
    }

    grid_sync(bar, c, 1u);

    // ---------------- PB: combine 4 -> d128 ----------------
    if (c < NC2) {
        const float* p = d32 + (size_t)(4 * c) * NXS * RB + tid;
        float x0v[NXS], x1v[NXS], x2v[NXS], x3v[NXS];
        #pragma unroll
        for (int i = 0; i < NXS; ++i) {
            x0v[i] = p[i * RB];
            x1v[i] = p[(size_t)NXS * RB + i * RB];
            x2v[i] = p[(size_t)2 * NXS * RB + i * RB];
            x3v[i] = p[(size_t)3 * NXS * RB + i * RB];
        }
        float* o = d128 + (size_t)c * NXS * RB + tid;
        #pragma unroll
        for (int i = 0; i < NXS; ++i) {
            float acc = x3v[i];
            #pragma unroll
            for (int k = 0; k < NXS; ++k) {
                acc = fmaf(P96[i * 8 + k], x0v[k], acc);
                acc = fmaf(P64[i * 8 + k], x1v[k], acc);
                acc = fmaf(P32[i * 8 + k], x2v[k], acc);
            }
            o[i * RB] = acc;
        }
    }

    grid_sync(bar, c, 2u);

    // ---------------- PC: serial scan over 128 super-chunks (block 0) -----
    if (c == 0) {
        float m[NXS][NXS];
        #pragma unroll
        for (int i = 0; i < NXS; ++i)
            #pragma unroll
            for (int j = 0; j < NXS; ++j) m[i][j] = P128[i * 8 + j];
        float s[NXS];
        #pragma unroll
        for (int i = 0; i < NXS; ++i) s[i] = x0[i * RB + tid];
        float P[4][NXS];  // rotating prefetch, depth 4
        #pragma unroll
        for (int sl = 0; sl < 4; ++sl) {
            const float* dp = d128 + (size_t)sl * NXS * RB + tid;
            #pragma unroll
            for (int i = 0; i < NXS; ++i) P[sl][i] = dp[i * RB];
        }
        for (int it = 0; it < NC2; it += 4) {
            #pragma unroll
            for (int sl = 0; sl < 4; ++sl) {
                const int cc = it + sl;
                float* sp = s128 + (size_t)cc * NXS * RB + tid;
                #pragma unroll
                for (int i = 0; i < NXS; ++i) sp[i * RB] = s[i];
                float d[NXS];
                #pragma unroll
                for (int i = 0; i < NXS; ++i) d[i] = P[sl][i];
                if (cc + 4 < NC2) {
                    const float* dp = d128 + (size_t)(cc + 4) * NXS * RB + tid;
                    #pragma unroll
                    for (int i = 0; i < NXS; ++i) P[sl][i] = dp[i * RB];
                }
                float ns[NXS];
                #pragma unroll
                for (int i = 0; i < NXS; ++i) {
                    float acc = d[i];
                    #pragma unroll
                    for (int k = 0; k < NXS; ++k) acc = fmaf(m[i][k], s[k], acc);
                    ns[i] = acc;
                }
                #pragma unroll
                for (int i = 0; i < NXS; ++i) s[i] = ns[i];
            }
        }
    }

    grid_sync(bar, c, 3u);

    // ---------------- PD: replay chunk c, write X and y ----------------
    {
        const int mm = c >> 2;
        const int p = c & 3;  // block-uniform
        float t[NXS];
        {
            const float* sp = s128 + (size_t)mm * NXS * RB + tid;
            #pragma unroll
            for (int i = 0; i < NXS; ++i) t[i] = sp[i * RB];
        }
        for (int q = 0; q < p; ++q) {  // advance start by q fine chunks
            const float* dp = d32 + (size_t)(4 * mm + q) * NXS * RB + tid;
            float nt[NXS];
            #pragma unroll
            for (int i = 0; i < NXS; ++i) {
                float acc = dp[i * RB];
                #pragma unroll
                for (int k = 0; k < NXS; ++k)
                    acc = fmaf(P32[i * 8 + k], t[k], acc);
                nt[i] = acc;
            }
            #pragma unroll
            for (int i = 0; i < NXS; ++i) t[i] = nt[i];
        }

        float a[NXS][NXS];
        #pragma unroll
        for (int i = 0; i < NXS; ++i)
            #pragma unroll
            for (int j = 0; j < NXS; ++j) a[i][j] = A[i * NXS + j];
        float b0[NXS], b1[NXS], c0[NXS], c1[NXS];
        #pragma unroll
        for (int i = 0; i < NXS; ++i) {
            b0[i] = Bu[i * NUI];
            b1[i] = Bu[i * NUI + 1];
        }
        #pragma unroll
        for (int k = 0; k < NXS; ++k) {
            c0[k] = Cy[k];
            c1[k] = Cy[NXS + k];
        }
        const float d00 = Dyu[0], d01 = Dyu[1], d10 = Dyu[2], d11 = Dyu[3];
        const float ym0 = ym[0], ym1 = ym[1], ys0 = ys[0], ys1 = ys[1];

        const float* up = u + (size_t)c * LF * NUI * RB + tid;
        float* Xp = X + (size_t)c * LF * NXS * RB + tid;
        float* Yp = Y + (size_t)c * LF * NYO * RB + tid;
        #pragma unroll 4
        for (int j = 0; j < LF; ++j) {
            const float u0 = (up[0]  - um0) * is0;
            const float u1 = (up[RB] - um1) * is1;
            up += NUI * RB;
            #pragma unroll
            for (int i = 0; i < NXS; ++i)
                __builtin_nontemporal_store(t[i], Xp + i * RB);
            Xp += NXS * RB;
            float y0 = fmaf(d00, u0, d01 * u1);
            float y1 = fmaf(d10, u0, d11 * u1);
            #pragma unroll
            for (int k = 0; k < NXS; ++k) {
                y0 = fmaf(c0[k], t[k], y0);
                y1 = fmaf(c1[k], t[k], y1);
            }
            __builtin_nontemporal_store(fmaf(y0, ys0, ym0), Yp);
            __builtin_nontemporal_store(fmaf(y1, ys1, ym1), Yp + RB);
            Yp += NYO * RB;
            float nt[NXS];
            #pragma unroll
            for (int i = 0; i < NXS; ++i) {
                float acc = fmaf(b0[i], u0, b1[i] * u1);
                #pragma unroll
                for (int k = 0; k < NXS; ++k) acc = fmaf(a[i][k], t[k], acc);
                nt[i] = acc;
            }
            #pragma unroll
            for (int i = 0; i < NXS; ++i) t[i] = nt[i];
        }
    }
}

extern "C" void kernel_launch(void* const* d_in, const int* in_sizes, int n_in,
                              void* d_out, int out_size, void* d_ws, size_t ws_size,
                              hipStream_t stream) {
    const float* u   = (const float*)d_in[0];
    const float* x0  = (const float*)d_in[1];
    const float* A   = (const float*)d_in[2];
    const float* Bu  = (const float*)d_in[3];
    const float* Cy  = (const float*)d_in[4];
    const float* Dyu = (const float*)d_in[5];
    const float* um  = (const float*)d_in[6];
    const float* us  = (const float*)d_in[7];
    const float* ym  = (const float*)d_in[8];
    const float* ys  = (const float*)d_in[9];

    float* Y = (float*)d_out;                    // (N, NY, R)
    float* X = Y + (size_t)NSTEPS * NYO * RB;    // (N, NX, R)

    float* ws   = (float*)d_ws;
    float* d32  = ws;                            // NC1*NX*R = 4 MB
    float* d128 = d32 + (size_t)NC1 * NXS * RB;  // 1 MB
    float* s128 = d128 + (size_t)NC2 * NXS * RB; // 1 MB
    unsigned* bar = (unsigned*)(s128 + (size_t)NC2 * NXS * RB);

    hipMemsetAsync(bar, 0, (NGRP + 1) * 32 * sizeof(unsigned), stream);
    fused_scan_k<<<NBLK, 256, 0, stream>>>(u, x0, A, Bu, Cy, Dyu, um, us, ym, ys,
                                           Y, X, d32, d128, s128, bar);
}